// Round 5
// baseline (944.018 us; speedup 1.0000x reference)
//
#include <hip/hip_runtime.h>
#include <hip/hip_bf16.h>

// ---------------- problem constants ----------------
#define Bz   32
#define Nn_  577
#define Np   640                    // 577 padded to 5*128
#define Cc   768
#define Hh   3072
#define Mrows (Bz * Nn_)            // 18464
#define OUT_X (Mrows * Cc)          // 14,180,352 floats
#define SCALE 0.03608439182435161f  // 768^-0.5

typedef unsigned short ushort_t;
typedef short short8 __attribute__((ext_vector_type(8)));
typedef float f32x4 __attribute__((ext_vector_type(4)));

__device__ __forceinline__ ushort_t f2b(float f) {
    __hip_bfloat16 h = __float2bfloat16(f);
    return *reinterpret_cast<ushort_t*>(&h);
}

// ---------------- async global->LDS (16B per lane) ----------------
__device__ __forceinline__ void gl16(const ushort_t* g, ushort_t* l) {
    __builtin_amdgcn_global_load_lds(
        (const __attribute__((address_space(1))) void*)g,
        (__attribute__((address_space(3))) void*)l, 16, 0, 0);
}

// ---------------- block reduction helpers (256-thread blocks) ----------------
__device__ __forceinline__ float bsum(float v, float* sm) {
    #pragma unroll
    for (int o = 32; o > 0; o >>= 1) v += __shfl_down(v, o, 64);
    int lane = threadIdx.x & 63, wid = threadIdx.x >> 6;
    if (lane == 0) sm[wid] = v;
    __syncthreads();
    float r = sm[0] + sm[1] + sm[2] + sm[3];
    __syncthreads();
    return r;
}
__device__ __forceinline__ float bmax(float v, float* sm) {
    #pragma unroll
    for (int o = 32; o > 0; o >>= 1) v = fmaxf(v, __shfl_down(v, o, 64));
    int lane = threadIdx.x & 63, wid = threadIdx.x >> 6;
    if (lane == 0) sm[wid] = v;
    __syncthreads();
    float r = fmaxf(fmaxf(sm[0], sm[1]), fmaxf(sm[2], sm[3]));
    __syncthreads();
    return r;
}

// ---------------- fp32 -> bf16 convert ----------------
__global__ void cvt_kernel(const float* __restrict__ in, ushort_t* __restrict__ out, int n) {
    int i = blockIdx.x * 256 + threadIdx.x;
    if (i < n) out[i] = f2b(in[i]);
}

// ---------------- LayerNorm: fp32 in, bf16 out ----------------
__global__ void ln_bf16(const float* __restrict__ x, const float* __restrict__ w,
                        const float* __restrict__ b, ushort_t* __restrict__ out) {
    __shared__ float sm[8];
    long long row = blockIdx.x;
    const float* xr = x + row * Cc;
    float v[3]; float s = 0.f;
    #pragma unroll
    for (int i = 0; i < 3; ++i) { v[i] = xr[threadIdx.x + i * 256]; s += v[i]; }
    float mu = bsum(s, sm) * (1.f / (float)Cc);
    float sq = 0.f;
    #pragma unroll
    for (int i = 0; i < 3; ++i) { float d = v[i] - mu; sq += d * d; }
    float var = bsum(sq, sm + 4) * (1.f / (float)Cc);
    float inv = rsqrtf(var + 1e-5f);
    ushort_t* orow = out + row * Cc;
    #pragma unroll
    for (int i = 0; i < 3; ++i) {
        int c = threadIdx.x + i * 256;
        orow[c] = f2b((v[i] - mu) * inv * w[c] + b[c]);
    }
}

// ---------------- softmax: fp32 Sf (ld 640, 577 valid) -> bf16 Sb (zero-padded) + tok ----------------
__global__ void softmax_bf16(const float* __restrict__ Sf, ushort_t* __restrict__ Sb,
                             float* __restrict__ tok) {
    __shared__ float sm[8];
    long long row = blockIdx.x;
    int b_l = (int)(row / Nn_), r = (int)(row - (long long)b_l * Nn_);
    const float* src = Sf + row * Np;
    ushort_t* dst = Sb + row * Np;
    float v[3]; float mx = -1e30f;
    #pragma unroll
    for (int i = 0; i < 3; ++i) {
        int c = threadIdx.x + i * 256;
        v[i] = (c < Nn_) ? src[c] : -1e30f;
        mx = fmaxf(mx, v[i]);
    }
    mx = bmax(mx, sm);
    float s = 0.f;
    #pragma unroll
    for (int i = 0; i < 3; ++i) {
        int c = threadIdx.x + i * 256;
        v[i] = (c < Nn_) ? expf(v[i] - mx) : 0.f;
        s += v[i];
    }
    s = bsum(s, sm + 4);
    float inv = 1.f / s;
    #pragma unroll
    for (int i = 0; i < 3; ++i) {
        int c = threadIdx.x + i * 256;
        float p = v[i] * inv;
        if (c < Np) dst[c] = (c < Nn_) ? f2b(p) : (ushort_t)0;
        if (r == 0 && c >= 1 && c < Nn_) tok[(long long)b_l * 576 + (c - 1)] = p;
    }
}

// ---------------- bf16 MFMA GEMM: C[m,n] = alpha*sum_k A[m,k]*B[n,k] (+epilogue) ----------------
// A: M x K rows (lda), row-clamped. B: Nv x K rows (ldb), row-clamped.
// z-dim: batch index (strides sAb/sBb/sOb).
// LDS XOR swizzle: lds quarter slot q' of row r holds global quarter q'^((r>>1)&3).
// Bank word-index = (r*16 + 4q') mod 32 depends on (r&1, q') only; (r>>1)&3 spreads
// the 8 same-parity rows of a 16-row fragment group evenly over all 4 quarters
// -> 2-way bank aliasing (free per m136). (r&3 swizzle was WRONG: 4-way.)
#define EPS_STORE  0
#define EPS_X2     1
#define EPS_GELU   2
#define EPS_ACC    3
#define EPS_QKV    4

template<int EPI, typename OutT>
__global__ __launch_bounds__(256)
void mm_bf16(const ushort_t* __restrict__ A, long long sAb, int lda, int M,
             const ushort_t* __restrict__ B, long long sBb, int ldb, int Nv,
             const float* __restrict__ bias,
             OutT* __restrict__ O, long long sOb, int ldo,
             int K, float alpha,
             ushort_t* __restrict__ qQ, ushort_t* __restrict__ qK, ushort_t* __restrict__ qV)
{
    __shared__ __align__(16) ushort_t As[128 * 32];
    __shared__ __align__(16) ushort_t Bs[128 * 32];
    const int z = blockIdx.z;
    A += (long long)z * sAb; B += (long long)z * sBb;
    if (O) O += (long long)z * sOb;
    const int n0 = blockIdx.x * 128;
    const int m0 = blockIdx.y * 128;
    const int tid = threadIdx.x;
    const int lane = tid & 63;
    const int wv = tid >> 6;
    const int wr = (wv >> 1) << 6;       // wave row offset in tile
    const int wc = (wv & 1) << 6;        // wave col offset in tile
    const int fr = lane & 15;
    const int kq = lane >> 4;            // k-quarter 0..3

    // staging: LDS chunk element e (ushorts) -> row = e>>5, lds quarter q' = (e&31)>>3,
    // source global quarter q = q' ^ ((row>>1)&3).
    const int e0 = tid * 8, e1 = 2048 + tid * 8;
    const int ra0 = e0 >> 5, qa0 = (((e0 & 31) >> 3) ^ ((ra0 >> 1) & 3)) << 3;
    const int ra1 = e1 >> 5, qa1 = (((e1 & 31) >> 3) ^ ((ra1 >> 1) & 3)) << 3;
    const ushort_t* Ag0 = A + (long long)min(m0 + ra0, M - 1) * lda + qa0;
    const ushort_t* Ag1 = A + (long long)min(m0 + ra1, M - 1) * lda + qa1;
    const ushort_t* Bg0 = B + (long long)min(n0 + ra0, Nv - 1) * ldb + qa0;
    const ushort_t* Bg1 = B + (long long)min(n0 + ra1, Nv - 1) * ldb + qa1;

    f32x4 acc[4][4] = {};

    for (int k0 = 0; k0 < K; k0 += 32) {
        gl16(Ag0 + k0, &As[e0]);
        gl16(Ag1 + k0, &As[e1]);
        gl16(Bg0 + k0, &Bs[e0]);
        gl16(Bg1 + k0, &Bs[e1]);
        __syncthreads();
        short8 af[4], bfr[4];
        #pragma unroll
        for (int i = 0; i < 4; ++i) {
            int r = wr + i * 16 + fr;
            af[i] = *(const short8*)&As[r * 32 + ((kq ^ ((r >> 1) & 3)) << 3)];
        }
        #pragma unroll
        for (int j = 0; j < 4; ++j) {
            int r = wc + j * 16 + fr;
            bfr[j] = *(const short8*)&Bs[r * 32 + ((kq ^ ((r >> 1) & 3)) << 3)];
        }
        #pragma unroll
        for (int i = 0; i < 4; ++i)
            #pragma unroll
            for (int j = 0; j < 4; ++j)
                acc[i][j] = __builtin_amdgcn_mfma_f32_16x16x32_bf16(af[i], bfr[j], acc[i][j], 0, 0, 0);
        __syncthreads();
    }

    // epilogue: C row m = m0+wr+i*16+(lane>>4)*4+r ; col n = n0+wc+j*16+(lane&15)
    #pragma unroll
    for (int i = 0; i < 4; ++i) {
        int mb = m0 + wr + i * 16 + (lane >> 4) * 4;
        #pragma unroll
        for (int j = 0; j < 4; ++j) {
            int n = n0 + wc + j * 16 + fr;
            if (n >= Nv) continue;
            f32x4 v4 = acc[i][j];
            #pragma unroll
            for (int r = 0; r < 4; ++r) {
                int m = mb + r;
                if (m >= M) continue;
                float v = v4[r] * alpha;
                if constexpr (EPI == EPS_QKV) {
                    int b_l = m / Nn_, rr = m - b_l * Nn_;
                    if (n < Cc)            qQ[(long long)m * Cc + n] = f2b(v);
                    else if (n < 2 * Cc)   qK[(long long)m * Cc + (n - Cc)] = f2b(v);
                    else                   qV[((long long)b_l * Cc + (n - 2 * Cc)) * Np + rr] = f2b(v);
                } else {
                    if (bias) v += bias[n];
                    if constexpr (EPI == EPS_X2) v *= 2.f;
                    if constexpr (EPI == EPS_GELU) v = 0.5f * v * (1.f + erff(v * 0.70710678118654752f));
                    long long oi = (long long)m * ldo + n;
                    if constexpr (EPI == EPS_ACC) {
                        O[oi] += v;               // single owner per output, no atomics
                    } else {
                        if constexpr (sizeof(OutT) == 2) O[oi] = (OutT)f2b(v);
                        else                             O[oi] = (OutT)v;
                    }
                }
            }
        }
    }
}

// ---------------- launcher ----------------
extern "C" void kernel_launch(void* const* d_in, const int* in_sizes, int n_in,
                              void* d_out, int out_size, void* d_ws, size_t ws_size,
                              hipStream_t stream) {
    const float* x      = (const float*)d_in[0];
    const float* n1w    = (const float*)d_in[1];
    const float* n1b    = (const float*)d_in[2];
    const float* qkv_w  = (const float*)d_in[3];
    const float* proj_w = (const float*)d_in[4];
    const float* proj_b = (const float*)d_in[5];
    const float* n2w    = (const float*)d_in[6];
    const float* n2b    = (const float*)d_in[7];
    const float* fc1w   = (const float*)d_in[8];
    const float* fc1b   = (const float*)d_in[9];
    const float* fc2w   = (const float*)d_in[10];
    const float* fc2b   = (const float*)d_in[11];
    float* out = (float*)d_out;
    float* x2  = out;
    float* tok = out + OUT_X;

    // ---- persistent bf16 weights at ws start ----
    char* ws = (char*)d_ws;
    const long long nWq = (long long)3 * Cc * Cc;
    const long long nWp = (long long)Cc * Cc;
    const long long nW1 = (long long)Hh * Cc;
    const long long nW2 = (long long)Cc * Hh;
    ushort_t* wq = (ushort_t*)ws;
    ushort_t* wp = wq + nWq;
    ushort_t* w1 = wp + nWp;
    ushort_t* w2 = w1 + nW1;
    const long long WBYTES = 2 * (nWq + nWp + nW1 + nW2); // 14,155,776
    char* dyn = ws + WBYTES;
    long long avail = (long long)ws_size - WBYTES;

    // ---- adaptive sizes (prefer no chunking: G=32, CH=full) ----
    const long long perG = 3LL * Nn_ * Cc * 2 + (long long)Cc * Np * 2
                         + (long long)Nn_ * Np * 4 + (long long)Nn_ * Np * 2;
    int G = 1;
    { const int o[6] = {32, 16, 8, 4, 2, 1};
      for (int i = 0; i < 6; ++i) if ((long long)o[i] * perG <= avail) { G = o[i]; break; } }
    int CH = Nn_;
    { const int o[6] = {32, 16, 8, 4, 2, 1};
      for (int i = 0; i < 6; ++i) if ((long long)o[i] * Nn_ * (Cc + Hh) * 2 <= avail) { CH = o[i] * Nn_; break; } }

    // phase A layout: hbf/Yt | Q | Kb | Vt | Sf | Sb
    ushort_t* hbf = (ushort_t*)dyn;
    ushort_t* Q   = hbf + (long long)G * Nn_ * Cc;
    ushort_t* Kb  = Q   + (long long)G * Nn_ * Cc;
    ushort_t* Vt  = Kb  + (long long)G * Nn_ * Cc;
    float*    Sf  = (float*)(Vt + (long long)G * Cc * Np);
    ushort_t* Sb  = (ushort_t*)(Sf + (long long)G * Nn_ * Np);
    ushort_t* Yt  = hbf;
    // phase B layout: g | t
    ushort_t* g = (ushort_t*)dyn;
    ushort_t* t = g + (long long)CH * Cc;

    // ---- weight conversion (every call; ws is re-poisoned) ----
    cvt_kernel<<<(int)((nWq + 255) / 256), 256, 0, stream>>>(qkv_w, wq, (int)nWq);
    cvt_kernel<<<(int)((nWp + 255) / 256), 256, 0, stream>>>(proj_w, wp, (int)nWp);
    cvt_kernel<<<(int)((nW1 + 255) / 256), 256, 0, stream>>>(fc1w, w1, (int)nW1);
    cvt_kernel<<<(int)((nW2 + 255) / 256), 256, 0, stream>>>(fc2w, w2, (int)nW2);

    // ================= phase A: attention per group of G batches =================
    for (int b0 = 0; b0 < Bz; b0 += G) {
        const int MR = G * Nn_;
        const int myM = (MR + 127) / 128;

        ln_bf16<<<MR, 256, 0, stream>>>(x + (long long)b0 * Nn_ * Cc, n1w, n1b, hbf);

        // qkv: (MR x 2304 x 768), scatter to Q | Kb | Vt
        mm_bf16<EPS_QKV, float><<<dim3(18, myM, 1), 256, 0, stream>>>(
            hbf, 0, Cc, MR, wq, 0, Cc, 3 * Cc, nullptr,
            (float*)nullptr, 0, 0, Cc, 1.f, Q, Kb, Vt);

        // Sf = scale * Q @ K^T per batch (577x577 valid, ld 640)
        mm_bf16<EPS_STORE, float><<<dim3(5, 5, G), 256, 0, stream>>>(
            Q, (long long)Nn_ * Cc, Cc, Nn_, Kb, (long long)Nn_ * Cc, Cc, Nn_, nullptr,
            Sf, (long long)Nn_ * Np, Np, Cc, SCALE, nullptr, nullptr, nullptr);

        softmax_bf16<<<MR, 256, 0, stream>>>(Sf, Sb, tok + (long long)b0 * 576);

        // Yt[c, n] = sum_m Vt[c, m] * Sb[n, m]  (M=768, N=577 valid, K=640)
        mm_bf16<EPS_STORE, ushort_t><<<dim3(5, 6, G), 256, 0, stream>>>(
            Vt, (long long)Cc * Np, Np, Cc, Sb, (long long)Nn_ * Np, Np, Nn_, nullptr,
            Yt, (long long)Cc * Nn_, Nn_, Np, 1.f, nullptr, nullptr, nullptr);

        // x2 = 2*(Yt_flat @ proj_w^T + proj_b) -> d_out rows of group (fp32)
        mm_bf16<EPS_X2, float><<<dim3(6, myM, 1), 256, 0, stream>>>(
            Yt, 0, Cc, MR, wp, 0, Cc, Cc, proj_b,
            x2 + (long long)b0 * Nn_ * Cc, 0, Cc, Cc, 1.f, nullptr, nullptr, nullptr);
    }

    // ================= phase B: MLP per chunk of CH rows =================
    for (int c0 = 0; c0 < Mrows; c0 += CH) {
        const int cn = (Mrows - c0 < CH) ? (Mrows - c0) : CH;
        const int myC = (cn + 127) / 128;

        ln_bf16<<<cn, 256, 0, stream>>>(x2 + (long long)c0 * Cc, n2w, n2b, g);

        // t = gelu(g @ fc1^T + b1)  (cn x 3072 x 768), bf16
        mm_bf16<EPS_GELU, ushort_t><<<dim3(24, myC, 1), 256, 0, stream>>>(
            g, 0, Cc, cn, w1, 0, Cc, Hh, fc1b,
            t, 0, Hh, Cc, 1.f, nullptr, nullptr, nullptr);

        // x2 += t @ fc2^T + b2  (cn x 768 x 3072), non-atomic accumulate, single owner
        mm_bf16<EPS_ACC, float><<<dim3(6, myC, 1), 256, 0, stream>>>(
            t, 0, Hh, cn, w2, 0, Hh, Cc, fc2b,
            x2 + (long long)c0 * Cc, 0, Cc, Hh, 1.f, nullptr, nullptr, nullptr);
    }
}

// Round 6
// 925.412 us; speedup vs baseline: 1.0201x; 1.0201x over previous
//
#include <hip/hip_runtime.h>
#include <hip/hip_bf16.h>

// ---------------- problem constants ----------------
#define Bz   32
#define Nn_  577
#define Np   640                    // 577 padded to 5*128
#define Cc   768
#define Hh   3072
#define Mrows (Bz * Nn_)            // 18464
#define OUT_X (Mrows * Cc)          // 14,180,352 floats
#define SCALE 0.03608439182435161f  // 768^-0.5

typedef unsigned short ushort_t;
typedef short short8 __attribute__((ext_vector_type(8)));
typedef float f32x4 __attribute__((ext_vector_type(4)));

__device__ __forceinline__ ushort_t f2b(float f) {
    __hip_bfloat16 h = __float2bfloat16(f);
    return *reinterpret_cast<ushort_t*>(&h);
}

// ---------------- async global->LDS (16B per lane) ----------------
__device__ __forceinline__ void gl16(const ushort_t* g, ushort_t* l) {
    __builtin_amdgcn_global_load_lds(
        (const __attribute__((address_space(1))) void*)g,
        (__attribute__((address_space(3))) void*)l, 16, 0, 0);
}

// ---------------- block reduction helpers (256-thread blocks) ----------------
__device__ __forceinline__ float bsum(float v, float* sm) {
    #pragma unroll
    for (int o = 32; o > 0; o >>= 1) v += __shfl_down(v, o, 64);
    int lane = threadIdx.x & 63, wid = threadIdx.x >> 6;
    if (lane == 0) sm[wid] = v;
    __syncthreads();
    float r = sm[0] + sm[1] + sm[2] + sm[3];
    __syncthreads();
    return r;
}
__device__ __forceinline__ float bmax(float v, float* sm) {
    #pragma unroll
    for (int o = 32; o > 0; o >>= 1) v = fmaxf(v, __shfl_down(v, o, 64));
    int lane = threadIdx.x & 63, wid = threadIdx.x >> 6;
    if (lane == 0) sm[wid] = v;
    __syncthreads();
    float r = fmaxf(fmaxf(sm[0], sm[1]), fmaxf(sm[2], sm[3]));
    __syncthreads();
    return r;
}

// ---------------- fp32 -> bf16 convert ----------------
__global__ void cvt_kernel(const float* __restrict__ in, ushort_t* __restrict__ out, int n) {
    int i = blockIdx.x * 256 + threadIdx.x;
    if (i < n) out[i] = f2b(in[i]);
}

// ---------------- LayerNorm: fp32 in, bf16 out ----------------
__global__ void ln_bf16(const float* __restrict__ x, const float* __restrict__ w,
                        const float* __restrict__ b, ushort_t* __restrict__ out) {
    __shared__ float sm[8];
    long long row = blockIdx.x;
    const float* xr = x + row * Cc;
    float v[3]; float s = 0.f;
    #pragma unroll
    for (int i = 0; i < 3; ++i) { v[i] = xr[threadIdx.x + i * 256]; s += v[i]; }
    float mu = bsum(s, sm) * (1.f / (float)Cc);
    float sq = 0.f;
    #pragma unroll
    for (int i = 0; i < 3; ++i) { float d = v[i] - mu; sq += d * d; }
    float var = bsum(sq, sm + 4) * (1.f / (float)Cc);
    float inv = rsqrtf(var + 1e-5f);
    ushort_t* orow = out + row * Cc;
    #pragma unroll
    for (int i = 0; i < 3; ++i) {
        int c = threadIdx.x + i * 256;
        orow[c] = f2b((v[i] - mu) * inv * w[c] + b[c]);
    }
}

// ---------------- softmax: fp32 Sf (ld 640, 577 valid) -> bf16 Sb (zero-padded) + tok ----------------
__global__ void softmax_bf16(const float* __restrict__ Sf, ushort_t* __restrict__ Sb,
                             float* __restrict__ tok) {
    __shared__ float sm[8];
    long long row = blockIdx.x;
    int b_l = (int)(row / Nn_), r = (int)(row - (long long)b_l * Nn_);
    const float* src = Sf + row * Np;
    ushort_t* dst = Sb + row * Np;
    float v[3]; float mx = -1e30f;
    #pragma unroll
    for (int i = 0; i < 3; ++i) {
        int c = threadIdx.x + i * 256;
        v[i] = (c < Nn_) ? src[c] : -1e30f;
        mx = fmaxf(mx, v[i]);
    }
    mx = bmax(mx, sm);
    float s = 0.f;
    #pragma unroll
    for (int i = 0; i < 3; ++i) {
        int c = threadIdx.x + i * 256;
        v[i] = (c < Nn_) ? expf(v[i] - mx) : 0.f;
        s += v[i];
    }
    s = bsum(s, sm + 4);
    float inv = 1.f / s;
    #pragma unroll
    for (int i = 0; i < 3; ++i) {
        int c = threadIdx.x + i * 256;
        float p = v[i] * inv;
        if (c < Np) dst[c] = (c < Nn_) ? f2b(p) : (ushort_t)0;
        if (r == 0 && c >= 1 && c < Nn_) tok[(long long)b_l * 576 + (c - 1)] = p;
    }
}

// ---------------- bf16 MFMA GEMM: C[m,n] = alpha*sum_k A[m,k]*B[n,k] (+epilogue) ----------------
// BMt: tile rows (128 for wide-N throughput GEMMs, 64 for skinny-N latency GEMMs —
// doubles the grid for latency hiding; N/BN refetch ratio unchanged).
// A: M x K rows (lda), row-clamped. B: Nv x K rows (ldb), row-clamped. BN fixed 128.
// LDS XOR swizzle: quarter slot q' of row r holds global quarter q'^((r>>1)&3)
// -> 2-way bank aliasing (free, m136). Verified: conflicts == 0 in R5.
#define EPS_STORE  0
#define EPS_X2     1
#define EPS_GELU   2
#define EPS_ACC    3
#define EPS_QKV    4

template<int BMt, int EPI, typename OutT>
__global__ __launch_bounds__(256)
void mm_bf16(const ushort_t* __restrict__ A, long long sAb, int lda, int M,
             const ushort_t* __restrict__ B, long long sBb, int ldb, int Nv,
             const float* __restrict__ bias,
             OutT* __restrict__ O, long long sOb, int ldo,
             int K, float alpha,
             ushort_t* __restrict__ qQ, ushort_t* __restrict__ qK, ushort_t* __restrict__ qV)
{
    constexpr int FRI = BMt / 32;        // fragment rows per wave (4 or 2)
    constexpr int ACH = BMt / 64;        // A staging chunks (2 or 1)
    __shared__ __align__(16) ushort_t As[BMt * 32];
    __shared__ __align__(16) ushort_t Bs[128 * 32];
    const int z = blockIdx.z;
    A += (long long)z * sAb; B += (long long)z * sBb;
    if (O) O += (long long)z * sOb;
    const int n0 = blockIdx.x * 128;
    const int m0 = blockIdx.y * BMt;
    const int tid = threadIdx.x;
    const int lane = tid & 63;
    const int wv = tid >> 6;
    const int wr = (wv >> 1) * (BMt / 2);   // wave row offset in tile
    const int wc = (wv & 1) << 6;           // wave col offset in tile
    const int fr = lane & 15;
    const int kq = lane >> 4;               // k-quarter 0..3

    // staging: chunk element e -> row = e>>5, lds quarter q' = (e&31)>>3,
    // source global quarter q = q' ^ ((row>>1)&3).
    const ushort_t* Ag[ACH];
    const ushort_t* Bg[2];
    int eA[ACH], eB[2];
    #pragma unroll
    for (int c = 0; c < ACH; ++c) {
        int e = c * 2048 + tid * 8;
        int ra = e >> 5, qa = (((e & 31) >> 3) ^ ((ra >> 1) & 3)) << 3;
        eA[c] = e;
        Ag[c] = A + (long long)min(m0 + ra, M - 1) * lda + qa;
    }
    #pragma unroll
    for (int c = 0; c < 2; ++c) {
        int e = c * 2048 + tid * 8;
        int ra = e >> 5, qa = (((e & 31) >> 3) ^ ((ra >> 1) & 3)) << 3;
        eB[c] = e;
        Bg[c] = B + (long long)min(n0 + ra, Nv - 1) * ldb + qa;
    }

    f32x4 acc[FRI][4] = {};

    for (int k0 = 0; k0 < K; k0 += 32) {
        #pragma unroll
        for (int c = 0; c < ACH; ++c) gl16(Ag[c] + k0, &As[eA[c]]);
        #pragma unroll
        for (int c = 0; c < 2; ++c)   gl16(Bg[c] + k0, &Bs[eB[c]]);
        __syncthreads();
        short8 af[FRI], bfr[4];
        #pragma unroll
        for (int i = 0; i < FRI; ++i) {
            int r = wr + i * 16 + fr;
            af[i] = *(const short8*)&As[r * 32 + ((kq ^ ((r >> 1) & 3)) << 3)];
        }
        #pragma unroll
        for (int j = 0; j < 4; ++j) {
            int r = wc + j * 16 + fr;
            bfr[j] = *(const short8*)&Bs[r * 32 + ((kq ^ ((r >> 1) & 3)) << 3)];
        }
        #pragma unroll
        for (int i = 0; i < FRI; ++i)
            #pragma unroll
            for (int j = 0; j < 4; ++j)
                acc[i][j] = __builtin_amdgcn_mfma_f32_16x16x32_bf16(af[i], bfr[j], acc[i][j], 0, 0, 0);
        __syncthreads();
    }

    // epilogue: C row m = m0+wr+i*16+(lane>>4)*4+r ; col n = n0+wc+j*16+(lane&15)
    #pragma unroll
    for (int i = 0; i < FRI; ++i) {
        int mb = m0 + wr + i * 16 + (lane >> 4) * 4;
        #pragma unroll
        for (int j = 0; j < 4; ++j) {
            int n = n0 + wc + j * 16 + fr;
            if (n >= Nv) continue;
            f32x4 v4 = acc[i][j];
            #pragma unroll
            for (int r = 0; r < 4; ++r) {
                int m = mb + r;
                if (m >= M) continue;
                float v = v4[r] * alpha;
                if constexpr (EPI == EPS_QKV) {
                    int b_l = m / Nn_, rr = m - b_l * Nn_;
                    if (n < Cc)            qQ[(long long)m * Cc + n] = f2b(v);
                    else if (n < 2 * Cc)   qK[(long long)m * Cc + (n - Cc)] = f2b(v);
                    else                   qV[((long long)b_l * Cc + (n - 2 * Cc)) * Np + rr] = f2b(v);
                } else {
                    if (bias) v += bias[n];
                    if constexpr (EPI == EPS_X2) v *= 2.f;
                    if constexpr (EPI == EPS_GELU) v = 0.5f * v * (1.f + erff(v * 0.70710678118654752f));
                    long long oi = (long long)m * ldo + n;
                    if constexpr (EPI == EPS_ACC) {
                        O[oi] += v;               // single owner per output, no atomics
                    } else {
                        if constexpr (sizeof(OutT) == 2) O[oi] = (OutT)f2b(v);
                        else                             O[oi] = (OutT)v;
                    }
                }
            }
        }
    }
}

// ---------------- launcher ----------------
extern "C" void kernel_launch(void* const* d_in, const int* in_sizes, int n_in,
                              void* d_out, int out_size, void* d_ws, size_t ws_size,
                              hipStream_t stream) {
    const float* x      = (const float*)d_in[0];
    const float* n1w    = (const float*)d_in[1];
    const float* n1b    = (const float*)d_in[2];
    const float* qkv_w  = (const float*)d_in[3];
    const float* proj_w = (const float*)d_in[4];
    const float* proj_b = (const float*)d_in[5];
    const float* n2w    = (const float*)d_in[6];
    const float* n2b    = (const float*)d_in[7];
    const float* fc1w   = (const float*)d_in[8];
    const float* fc1b   = (const float*)d_in[9];
    const float* fc2w   = (const float*)d_in[10];
    const float* fc2b   = (const float*)d_in[11];
    float* out = (float*)d_out;
    float* x2  = out;
    float* tok = out + OUT_X;

    // ---- persistent bf16 weights at ws start ----
    char* ws = (char*)d_ws;
    const long long nWq = (long long)3 * Cc * Cc;
    const long long nWp = (long long)Cc * Cc;
    const long long nW1 = (long long)Hh * Cc;
    const long long nW2 = (long long)Cc * Hh;
    ushort_t* wq = (ushort_t*)ws;
    ushort_t* wp = wq + nWq;
    ushort_t* w1 = wp + nWp;
    ushort_t* w2 = w1 + nW1;
    const long long WBYTES = 2 * (nWq + nWp + nW1 + nW2); // 14,155,776
    char* dyn = ws + WBYTES;
    long long avail = (long long)ws_size - WBYTES;

    // ---- adaptive sizes (prefer no chunking: G=32, CH=full) ----
    const long long perG = 3LL * Nn_ * Cc * 2 + (long long)Cc * Np * 2
                         + (long long)Nn_ * Np * 4 + (long long)Nn_ * Np * 2;
    int G = 1;
    { const int o[6] = {32, 16, 8, 4, 2, 1};
      for (int i = 0; i < 6; ++i) if ((long long)o[i] * perG <= avail) { G = o[i]; break; } }
    int CH = Nn_;
    { const int o[6] = {32, 16, 8, 4, 2, 1};
      for (int i = 0; i < 6; ++i) if ((long long)o[i] * Nn_ * (Cc + Hh) * 2 <= avail) { CH = o[i] * Nn_; break; } }

    // phase A layout: hbf/Yt | Q | Kb | Vt | Sf | Sb
    ushort_t* hbf = (ushort_t*)dyn;
    ushort_t* Q   = hbf + (long long)G * Nn_ * Cc;
    ushort_t* Kb  = Q   + (long long)G * Nn_ * Cc;
    ushort_t* Vt  = Kb  + (long long)G * Nn_ * Cc;
    float*    Sf  = (float*)(Vt + (long long)G * Cc * Np);
    ushort_t* Sb  = (ushort_t*)(Sf + (long long)G * Nn_ * Np);
    ushort_t* Yt  = hbf;
    // phase B layout: g | t
    ushort_t* g = (ushort_t*)dyn;
    ushort_t* t = g + (long long)CH * Cc;

    // ---- weight conversion (every call; ws is re-poisoned) ----
    cvt_kernel<<<(int)((nWq + 255) / 256), 256, 0, stream>>>(qkv_w, wq, (int)nWq);
    cvt_kernel<<<(int)((nWp + 255) / 256), 256, 0, stream>>>(proj_w, wp, (int)nWp);
    cvt_kernel<<<(int)((nW1 + 255) / 256), 256, 0, stream>>>(fc1w, w1, (int)nW1);
    cvt_kernel<<<(int)((nW2 + 255) / 256), 256, 0, stream>>>(fc2w, w2, (int)nW2);

    // ================= phase A: attention per group of G batches =================
    for (int b0 = 0; b0 < Bz; b0 += G) {
        const int MR = G * Nn_;
        const int my128 = (MR + 127) / 128;
        const int my64  = (MR + 63) / 64;

        ln_bf16<<<MR, 256, 0, stream>>>(x + (long long)b0 * Nn_ * Cc, n1w, n1b, hbf);

        // qkv: (MR x 2304 x 768), wide-N -> 128 tile; scatter to Q | Kb | Vt
        mm_bf16<128, EPS_QKV, float><<<dim3(18, my128, 1), 256, 0, stream>>>(
            hbf, 0, Cc, MR, wq, 0, Cc, 3 * Cc, nullptr,
            (float*)nullptr, 0, 0, Cc, 1.f, Q, Kb, Vt);

        // Sf = scale * Q @ K^T per batch (577x577 valid, ld 640), 64-row tiles
        mm_bf16<64, EPS_STORE, float><<<dim3(5, 10, G), 256, 0, stream>>>(
            Q, (long long)Nn_ * Cc, Cc, Nn_, Kb, (long long)Nn_ * Cc, Cc, Nn_, nullptr,
            Sf, (long long)Nn_ * Np, Np, Cc, SCALE, nullptr, nullptr, nullptr);

        softmax_bf16<<<MR, 256, 0, stream>>>(Sf, Sb, tok + (long long)b0 * 576);

        // Yt[c, n] = sum_m Vt[c, m] * Sb[n, m]  (M=768, N=577 valid, K=640), 64-row tiles
        mm_bf16<64, EPS_STORE, ushort_t><<<dim3(5, 12, G), 256, 0, stream>>>(
            Vt, (long long)Cc * Np, Np, Cc, Sb, (long long)Nn_ * Np, Np, Nn_, nullptr,
            Yt, (long long)Cc * Nn_, Nn_, Np, 1.f, nullptr, nullptr, nullptr);

        // x2 = 2*(Yt_flat @ proj_w^T + proj_b) -> d_out rows of group (fp32), 64-row tiles
        mm_bf16<64, EPS_X2, float><<<dim3(6, my64, 1), 256, 0, stream>>>(
            Yt, 0, Cc, MR, wp, 0, Cc, Cc, proj_b,
            x2 + (long long)b0 * Nn_ * Cc, 0, Cc, Cc, 1.f, nullptr, nullptr, nullptr);
    }

    // ================= phase B: MLP per chunk of CH rows =================
    for (int c0 = 0; c0 < Mrows; c0 += CH) {
        const int cn = (Mrows - c0 < CH) ? (Mrows - c0) : CH;
        const int c128 = (cn + 127) / 128;
        const int c64  = (cn + 63) / 64;

        ln_bf16<<<cn, 256, 0, stream>>>(x2 + (long long)c0 * Cc, n2w, n2b, g);

        // t = gelu(g @ fc1^T + b1)  (cn x 3072 x 768), wide-N -> 128 tile
        mm_bf16<128, EPS_GELU, ushort_t><<<dim3(24, c128, 1), 256, 0, stream>>>(
            g, 0, Cc, cn, w1, 0, Cc, Hh, fc1b,
            t, 0, Hh, Cc, 1.f, nullptr, nullptr, nullptr);

        // x2 += t @ fc2^T + b2  (cn x 768 x 3072), skinny-N -> 64-row tiles, 2x grid
        mm_bf16<64, EPS_ACC, float><<<dim3(6, c64, 1), 256, 0, stream>>>(
            t, 0, Hh, cn, w2, 0, Hh, Cc, fc2b,
            x2 + (long long)c0 * Cc, 0, Cc, Hh, 1.f, nullptr, nullptr, nullptr);
    }
}